// Round 1
// baseline (752.039 us; speedup 1.0000x reference)
//
#include <hip/hip_runtime.h>
#include <hip/hip_bf16.h>
#include <stdint.h>

#define B_   32
#define S_   577
#define SP   640
#define D_   1024
#define H_   16
#define DH   64
#define BH_  (B_*H_)
#define M_   (B_*S_)      // 18464
#define MP_  18560        // padded to 128
#define SCALE_ 0.125f

typedef __bf16 bf16;
typedef __bf16 bf16x8 __attribute__((ext_vector_type(8)));
typedef __bf16 bf16x4 __attribute__((ext_vector_type(4)));
typedef float  f32x4  __attribute__((ext_vector_type(4)));

__device__ __forceinline__ void gload16(const bf16* g, bf16* l) {
    __builtin_amdgcn_global_load_lds((__attribute__((address_space(1))) void*)g,
                                     (__attribute__((address_space(3))) void*)l, 16, 0, 0);
}

// ---------------- cast fp32 -> bf16 (vectorized float4 -> bf16x4) ----------------
__global__ void cast_kernel(const float* __restrict__ in, bf16* __restrict__ out, int n4) {
    int i = blockIdx.x * blockDim.x + threadIdx.x;
    if (i >= n4) return;
    float4 v = ((const float4*)in)[i];
    bf16x4 o;
    o[0] = (bf16)v.x; o[1] = (bf16)v.y; o[2] = (bf16)v.z; o[3] = (bf16)v.w;
    ((bf16x4*)out)[i] = o;
}

// ---------------- shared GEMM mainloop: C = A[M,K] * B[N,K]^T, 128x128 tile ----------------
__device__ __forceinline__ void gemm_core(const bf16* __restrict__ A, const bf16* __restrict__ B,
                                          int m0, int n0, int K,
                                          bf16* As, bf16* Bs, f32x4 acc[4][4]) {
    const int tid  = threadIdx.x;
    const int lane = tid & 63;
    const int wave = tid >> 6;
    const int wr = wave >> 1, wc = wave & 1;
    const int r16 = lane & 15, c4 = lane >> 4;

    #pragma unroll
    for (int i = 0; i < 4; ++i)
        #pragma unroll
        for (int j = 0; j < 4; ++j)
            #pragma unroll
            for (int r = 0; r < 4; ++r) acc[i][j][r] = 0.0f;

    const int nkt = K >> 6;
    for (int kt = 0; kt < nkt; ++kt) {
        // stage A and B 128x64 tiles into LDS via global_load_lds (16B/lane)
        #pragma unroll
        for (int i = 0; i < 4; ++i) {
            int li  = i * 256 + tid;
            int row = li >> 3, ch = li & 7;
            const bf16* ga = A + (size_t)(m0 + row) * K + kt * 64 + ch * 8;
            const bf16* gb = B + (size_t)(n0 + row) * K + kt * 64 + ch * 8;
            bf16* la = As + (size_t)(i * 256 + wave * 64) * 8;
            bf16* lb = Bs + (size_t)(i * 256 + wave * 64) * 8;
            gload16(ga, la);
            gload16(gb, lb);
        }
        __syncthreads();
        #pragma unroll
        for (int kk = 0; kk < 2; ++kk) {
            bf16x8 af[4], bfr[4];
            #pragma unroll
            for (int i = 0; i < 4; ++i)
                af[i] = *(const bf16x8*)(As + (wr * 64 + i * 16 + r16) * 64 + kk * 32 + c4 * 8);
            #pragma unroll
            for (int j = 0; j < 4; ++j)
                bfr[j] = *(const bf16x8*)(Bs + (wc * 64 + j * 16 + r16) * 64 + kk * 32 + c4 * 8);
            #pragma unroll
            for (int i = 0; i < 4; ++i)
                #pragma unroll
                for (int j = 0; j < 4; ++j)
                    acc[i][j] = __builtin_amdgcn_mfma_f32_16x16x32_bf16(af[i], bfr[j], acc[i][j], 0, 0, 0);
        }
        __syncthreads();
    }
}

// ---------------- QKV projection GEMM: [MP_,1024] x [3072,1024]^T ----------------
__global__ __launch_bounds__(256) void gemm_qkv(const bf16* __restrict__ A, const bf16* __restrict__ Bw,
                                                const float* __restrict__ qb, const float* __restrict__ kb,
                                                const float* __restrict__ vb,
                                                bf16* __restrict__ qbuf, bf16* __restrict__ kbuf,
                                                bf16* __restrict__ vT) {
    __shared__ __align__(16) bf16 As[128 * 64];
    __shared__ __align__(16) bf16 Bs[128 * 64];
    int bx = blockIdx.x;
    int bm = bx / 24, bn = bx % 24;
    f32x4 acc[4][4];
    gemm_core(A, Bw, bm * 128, bn * 128, 1024, As, Bs, acc);

    const int lane = threadIdx.x & 63;
    const int wave = threadIdx.x >> 6, wr = wave >> 1, wc = wave & 1;
    const int r16 = lane & 15, c4 = lane >> 4;
    #pragma unroll
    for (int j = 0; j < 4; ++j) {
        unsigned n = bn * 128 + wc * 64 + j * 16 + r16;
        unsigned which = n >> 10, e = n & 1023, h = e >> 6, dh = e & 63;
        float bias = (which == 0) ? qb[e] : (which == 1) ? kb[e] : vb[e];
        #pragma unroll
        for (int i = 0; i < 4; ++i) {
            #pragma unroll
            for (int r = 0; r < 4; ++r) {
                unsigned m = bm * 128 + wr * 64 + i * 16 + c4 * 4 + r;
                if (m >= M_) continue;
                unsigned b = m / 577u, s = m - b * 577u;
                unsigned bh = b * 16 + h;
                float val = acc[i][j][r] + bias;
                if (which == 0)       qbuf[((size_t)(bh * SP + s)) * 64 + dh] = (bf16)(val * SCALE_);
                else if (which == 1)  kbuf[((size_t)(bh * SP + s)) * 64 + dh] = (bf16)val;
                else                  vT [((size_t)(bh * 64 + dh)) * SP + s] = (bf16)val;
            }
        }
    }
}

// ---------------- output projection GEMM: [MP_,1024] x [1024,1024]^T + bias -> fp32 ----------------
__global__ __launch_bounds__(256) void gemm_out(const bf16* __restrict__ A, const bf16* __restrict__ Bw,
                                                const float* __restrict__ ob, float* __restrict__ out) {
    __shared__ __align__(16) bf16 As[128 * 64];
    __shared__ __align__(16) bf16 Bs[128 * 64];
    int bx = blockIdx.x;
    int bm = bx / 8, bn = bx % 8;
    f32x4 acc[4][4];
    gemm_core(A, Bw, bm * 128, bn * 128, 1024, As, Bs, acc);

    const int lane = threadIdx.x & 63;
    const int wave = threadIdx.x >> 6, wr = wave >> 1, wc = wave & 1;
    const int r16 = lane & 15, c4 = lane >> 4;
    #pragma unroll
    for (int j = 0; j < 4; ++j) {
        unsigned n = bn * 128 + wc * 64 + j * 16 + r16;
        float bias = ob[n];
        #pragma unroll
        for (int i = 0; i < 4; ++i) {
            #pragma unroll
            for (int r = 0; r < 4; ++r) {
                unsigned m = bm * 128 + wr * 64 + i * 16 + c4 * 4 + r;
                if (m < M_) out[(size_t)m * 1024 + n] = acc[i][j][r] + bias;
            }
        }
    }
}

// ---------------- flash attention: 1 block = (bh, 64-row q tile), 4 waves x 16 rows ----------------
__global__ __launch_bounds__(256) void attn_kernel(const bf16* __restrict__ qbuf, const bf16* __restrict__ kbuf,
                                                   const bf16* __restrict__ vT, bf16* __restrict__ obuf) {
    __shared__ __align__(16) bf16 Pl[4][16 * 72];
    int bx = blockIdx.x;
    int bh = bx / 10, qt = bx % 10;
    int b = bh >> 4, h = bh & 15;
    const int lane = threadIdx.x & 63, wave = threadIdx.x >> 6;
    const int r16 = lane & 15, c4 = lane >> 4;
    const int q0 = qt * 64 + wave * 16;

    const bf16* qb_ = qbuf + (size_t)bh * SP * 64;
    const bf16* kb_ = kbuf + (size_t)bh * SP * 64;
    const bf16* vb_ = vT   + (size_t)bh * 64 * SP;

    bf16x8 aq[2];
    #pragma unroll
    for (int c = 0; c < 2; ++c)
        aq[c] = *(const bf16x8*)(qb_ + (q0 + r16) * 64 + c * 32 + c4 * 8);

    float mi[4], li[4];
    f32x4 accO[4];
    #pragma unroll
    for (int r = 0; r < 4; ++r) { mi[r] = -3.0e38f; li[r] = 0.0f; }
    #pragma unroll
    for (int nt = 0; nt < 4; ++nt)
        #pragma unroll
        for (int r = 0; r < 4; ++r) accO[nt][r] = 0.0f;

    for (int kt = 0; kt < 10; ++kt) {
        // S = Q K^T for 16x64 tile (4 n-subtiles)
        f32x4 sc[4];
        #pragma unroll
        for (int nt = 0; nt < 4; ++nt) {
            #pragma unroll
            for (int r = 0; r < 4; ++r) sc[nt][r] = 0.0f;
            #pragma unroll
            for (int c = 0; c < 2; ++c) {
                bf16x8 kf = *(const bf16x8*)(kb_ + (kt * 64 + nt * 16 + r16) * 64 + c * 32 + c4 * 8);
                sc[nt] = __builtin_amdgcn_mfma_f32_16x16x32_bf16(aq[c], kf, sc[nt], 0, 0, 0);
            }
            // mask invalid key columns
            if (kt * 64 + nt * 16 + r16 >= S_) {
                #pragma unroll
                for (int r = 0; r < 4; ++r) sc[nt][r] = -1.0e30f;
            }
        }
        // online softmax (rows live in 16-lane groups sharing c4)
        float mnew[4], fsc[4], rs[4];
        #pragma unroll
        for (int r = 0; r < 4; ++r) {
            float mx = fmaxf(fmaxf(sc[0][r], sc[1][r]), fmaxf(sc[2][r], sc[3][r]));
            #pragma unroll
            for (int off = 8; off >= 1; off >>= 1) mx = fmaxf(mx, __shfl_xor(mx, off));
            mnew[r] = fmaxf(mi[r], mx);
            fsc[r]  = __expf(mi[r] - mnew[r]);
            rs[r] = 0.0f;
        }
        float p[4][4];
        #pragma unroll
        for (int nt = 0; nt < 4; ++nt)
            #pragma unroll
            for (int r = 0; r < 4; ++r) {
                p[nt][r] = __expf(sc[nt][r] - mnew[r]);
                rs[r] += p[nt][r];
            }
        #pragma unroll
        for (int r = 0; r < 4; ++r) {
            #pragma unroll
            for (int off = 8; off >= 1; off >>= 1) rs[r] += __shfl_xor(rs[r], off);
            li[r] = li[r] * fsc[r] + rs[r];
            mi[r] = mnew[r];
        }
        #pragma unroll
        for (int nt = 0; nt < 4; ++nt)
            #pragma unroll
            for (int r = 0; r < 4; ++r) accO[nt][r] *= fsc[r];

        // P tile -> LDS (transpose to A-fragment layout)
        #pragma unroll
        for (int nt = 0; nt < 4; ++nt)
            #pragma unroll
            for (int r = 0; r < 4; ++r)
                Pl[wave][(c4 * 4 + r) * 72 + nt * 16 + r16] = (bf16)p[nt][r];
        __syncthreads();
        bf16x8 pf[2];
        #pragma unroll
        for (int c = 0; c < 2; ++c)
            pf[c] = *(const bf16x8*)(&Pl[wave][r16 * 72 + c * 32 + c4 * 8]);

        // O += P V (vT is [64, SP] per bh)
        #pragma unroll
        for (int nt = 0; nt < 4; ++nt)
            #pragma unroll
            for (int c = 0; c < 2; ++c) {
                bf16x8 vf = *(const bf16x8*)(vb_ + (nt * 16 + r16) * SP + kt * 64 + c * 32 + c4 * 8);
                accO[nt] = __builtin_amdgcn_mfma_f32_16x16x32_bf16(pf[c], vf, accO[nt], 0, 0, 0);
            }
        __syncthreads();
    }

    // write O (bf16) into [B*S, 1024] layout for the output projection
    #pragma unroll
    for (int nt = 0; nt < 4; ++nt)
        #pragma unroll
        for (int r = 0; r < 4; ++r) {
            int s = qt * 64 + wave * 16 + c4 * 4 + r;
            if (s < S_) {
                float v = accO[nt][r] / li[r];
                obuf[((size_t)(b * S_ + s)) * 1024 + h * 64 + nt * 16 + r16] = (bf16)v;
            }
        }
}

extern "C" void kernel_launch(void* const* d_in, const int* in_sizes, int n_in,
                              void* d_out, int out_size, void* d_ws, size_t ws_size,
                              hipStream_t stream) {
    const float* hs = (const float*)d_in[0];
    const float* qw = (const float*)d_in[1];
    const float* qb = (const float*)d_in[2];
    const float* kw = (const float*)d_in[3];
    const float* kb = (const float*)d_in[4];
    const float* vw = (const float*)d_in[5];
    const float* vb = (const float*)d_in[6];
    const float* ow = (const float*)d_in[7];
    const float* ob = (const float*)d_in[8];

    char* ws = (char*)d_ws;
    size_t off = 0;
    auto alloc = [&](size_t bytes) { void* p = ws + off; off += (bytes + 255) & ~255UL; return p; };
    bf16* hsA  = (bf16*)alloc((size_t)MP_ * 1024 * 2);   // hidden bf16, reused as attention output
    bf16* wqkv = (bf16*)alloc((size_t)3072 * 1024 * 2);
    bf16* wo   = (bf16*)alloc((size_t)1024 * 1024 * 2);
    bf16* qbuf = (bf16*)alloc((size_t)BH_ * SP * 64 * 2);
    bf16* kbuf = (bf16*)alloc((size_t)BH_ * SP * 64 * 2);
    bf16* vT   = (bf16*)alloc((size_t)BH_ * 64 * SP * 2);

    // zero vT so padded key columns can never inject NaN/Inf into PV
    hipMemsetAsync(vT, 0, (size_t)BH_ * 64 * SP * 2, stream);

    int n4h = M_ * 1024 / 4;
    cast_kernel<<<(n4h + 255) / 256, 256, 0, stream>>>(hs, hsA, n4h);
    cast_kernel<<<1024, 256, 0, stream>>>(qw, wqkv,            262144);
    cast_kernel<<<1024, 256, 0, stream>>>(kw, wqkv + 1048576,  262144);
    cast_kernel<<<1024, 256, 0, stream>>>(vw, wqkv + 2097152,  262144);
    cast_kernel<<<1024, 256, 0, stream>>>(ow, wo,              262144);

    gemm_qkv<<<145 * 24, 256, 0, stream>>>(hsA, wqkv, qb, kb, vb, qbuf, kbuf, vT);
    attn_kernel<<<512 * 10, 256, 0, stream>>>(qbuf, kbuf, vT, hsA);
    gemm_out<<<145 * 8, 256, 0, stream>>>(hsA, wo, ob, (float*)d_out);
}

// Round 2
// 556.193 us; speedup vs baseline: 1.3521x; 1.3521x over previous
//
#include <hip/hip_runtime.h>
#include <hip/hip_bf16.h>
#include <stdint.h>

#define B_   32
#define S_   577
#define SP   640
#define D_   1024
#define H_   16
#define DH   64
#define BH_  (B_*H_)
#define M_   (B_*S_)      // 18464
#define MP_  18560        // padded to 128
#define SCALE_ 0.125f

typedef __bf16 bf16;
typedef __bf16 bf16x8 __attribute__((ext_vector_type(8)));
typedef __bf16 bf16x4 __attribute__((ext_vector_type(4)));
typedef float  f32x4  __attribute__((ext_vector_type(4)));

__device__ __forceinline__ void gload16(const bf16* g, bf16* l) {
    __builtin_amdgcn_global_load_lds((__attribute__((address_space(1))) void*)g,
                                     (__attribute__((address_space(3))) void*)l, 16, 0, 0);
}

// ---------------- cast fp32 -> bf16 (vectorized float4 -> bf16x4) ----------------
__global__ void cast_kernel(const float* __restrict__ in, bf16* __restrict__ out, int n4) {
    int i = blockIdx.x * blockDim.x + threadIdx.x;
    if (i >= n4) return;
    float4 v = ((const float4*)in)[i];
    bf16x4 o;
    o[0] = (bf16)v.x; o[1] = (bf16)v.y; o[2] = (bf16)v.z; o[3] = (bf16)v.w;
    ((bf16x4*)out)[i] = o;
}

// ---------------- shared GEMM mainloop: C = A[M,K] * B[N,K]^T, 128x128 tile ----------------
__device__ __forceinline__ void gemm_core(const bf16* __restrict__ A, const bf16* __restrict__ B,
                                          int m0, int n0, int K,
                                          bf16* As, bf16* Bs, f32x4 acc[4][4]) {
    const int tid  = threadIdx.x;
    const int lane = tid & 63;
    const int wave = tid >> 6;
    const int wr = wave >> 1, wc = wave & 1;
    const int r16 = lane & 15, c4 = lane >> 4;

    #pragma unroll
    for (int i = 0; i < 4; ++i)
        #pragma unroll
        for (int j = 0; j < 4; ++j)
            #pragma unroll
            for (int r = 0; r < 4; ++r) acc[i][j][r] = 0.0f;

    const int nkt = K >> 6;
    for (int kt = 0; kt < nkt; ++kt) {
        // stage A and B 128x64 tiles into LDS via global_load_lds (16B/lane)
        #pragma unroll
        for (int i = 0; i < 4; ++i) {
            int li  = i * 256 + tid;
            int row = li >> 3, ch = li & 7;
            const bf16* ga = A + (size_t)(m0 + row) * K + kt * 64 + ch * 8;
            const bf16* gb = B + (size_t)(n0 + row) * K + kt * 64 + ch * 8;
            bf16* la = As + (size_t)(i * 256 + wave * 64) * 8;
            bf16* lb = Bs + (size_t)(i * 256 + wave * 64) * 8;
            gload16(ga, la);
            gload16(gb, lb);
        }
        __syncthreads();
        #pragma unroll
        for (int kk = 0; kk < 2; ++kk) {
            bf16x8 af[4], bfr[4];
            #pragma unroll
            for (int i = 0; i < 4; ++i)
                af[i] = *(const bf16x8*)(As + (wr * 64 + i * 16 + r16) * 64 + kk * 32 + c4 * 8);
            #pragma unroll
            for (int j = 0; j < 4; ++j)
                bfr[j] = *(const bf16x8*)(Bs + (wc * 64 + j * 16 + r16) * 64 + kk * 32 + c4 * 8);
            #pragma unroll
            for (int i = 0; i < 4; ++i)
                #pragma unroll
                for (int j = 0; j < 4; ++j)
                    acc[i][j] = __builtin_amdgcn_mfma_f32_16x16x32_bf16(af[i], bfr[j], acc[i][j], 0, 0, 0);
        }
        __syncthreads();
    }
}

// ---------------- QKV projection GEMM: [MP_,1024] x [3072,1024]^T ----------------
__global__ __launch_bounds__(256) void gemm_qkv(const bf16* __restrict__ A, const bf16* __restrict__ Bw,
                                                const float* __restrict__ qb, const float* __restrict__ kb,
                                                const float* __restrict__ vb,
                                                bf16* __restrict__ qbuf, bf16* __restrict__ kbuf,
                                                bf16* __restrict__ vT) {
    __shared__ __align__(16) bf16 As[128 * 64];
    __shared__ __align__(16) bf16 Bs[128 * 64];
    int bx = blockIdx.x;
    int bm = bx / 24, bn = bx % 24;
    f32x4 acc[4][4];
    gemm_core(A, Bw, bm * 128, bn * 128, 1024, As, Bs, acc);

    const int lane = threadIdx.x & 63;
    const int wave = threadIdx.x >> 6, wr = wave >> 1, wc = wave & 1;
    const int r16 = lane & 15, c4 = lane >> 4;
    #pragma unroll
    for (int j = 0; j < 4; ++j) {
        unsigned n = bn * 128 + wc * 64 + j * 16 + r16;
        unsigned which = n >> 10, e = n & 1023, h = e >> 6, dh = e & 63;
        float bias = (which == 0) ? qb[e] : (which == 1) ? kb[e] : vb[e];
        #pragma unroll
        for (int i = 0; i < 4; ++i) {
            #pragma unroll
            for (int r = 0; r < 4; ++r) {
                unsigned m = bm * 128 + wr * 64 + i * 16 + c4 * 4 + r;
                if (m >= M_) continue;
                unsigned b = m / 577u, s = m - b * 577u;
                unsigned bh = b * 16 + h;
                float val = acc[i][j][r] + bias;
                if (which == 0)       qbuf[((size_t)(bh * SP + s)) * 64 + dh] = (bf16)(val * SCALE_);
                else if (which == 1)  kbuf[((size_t)(bh * SP + s)) * 64 + dh] = (bf16)val;
                else                  vT [((size_t)(bh * 64 + dh)) * SP + s] = (bf16)val;
            }
        }
    }
}

// ---------------- output projection GEMM: [MP_,1024] x [1024,1024]^T + bias -> fp32 ----------------
__global__ __launch_bounds__(256) void gemm_out(const bf16* __restrict__ A, const bf16* __restrict__ Bw,
                                                const float* __restrict__ ob, float* __restrict__ out) {
    __shared__ __align__(16) bf16 As[128 * 64];
    __shared__ __align__(16) bf16 Bs[128 * 64];
    int bx = blockIdx.x;
    int bm = bx / 8, bn = bx % 8;
    f32x4 acc[4][4];
    gemm_core(A, Bw, bm * 128, bn * 128, 1024, As, Bs, acc);

    const int lane = threadIdx.x & 63;
    const int wave = threadIdx.x >> 6, wr = wave >> 1, wc = wave & 1;
    const int r16 = lane & 15, c4 = lane >> 4;
    #pragma unroll
    for (int j = 0; j < 4; ++j) {
        unsigned n = bn * 128 + wc * 64 + j * 16 + r16;
        float bias = ob[n];
        #pragma unroll
        for (int i = 0; i < 4; ++i) {
            #pragma unroll
            for (int r = 0; r < 4; ++r) {
                unsigned m = bm * 128 + wr * 64 + i * 16 + c4 * 4 + r;
                if (m < M_) out[(size_t)m * 1024 + n] = acc[i][j][r] + bias;
            }
        }
    }
}

// ---------------- flash attention v2 ----------------
// Swapped QK^T (mfma(K,Q)): each lane owns ONE q-row (r16); softmax = local
// reduce + 2 shfls. 32 q-rows/wave, zero barriers (per-wave P tile in LDS with
// XOR swizzle on both sides), defer-max (THR=8), XCD-swizzled grid.
__global__ __launch_bounds__(256) void attn_kernel(const bf16* __restrict__ qbuf, const bf16* __restrict__ kbuf,
                                                   const bf16* __restrict__ vT, bf16* __restrict__ obuf) {
    __shared__ __align__(16) char Pls[4 * 2 * 2048];   // [wave][qf][16 rows][128B]
    const int orig = blockIdx.x;
    const int xcd = orig & 7;
    const int t   = orig >> 3;
    const int qt  = t % 5, bhg = t / 5;
    const int bh  = bhg * 8 + xcd;                     // all 5 q-blocks of a bh on one XCD
    const int b   = bh >> 4, h = bh & 15;
    const int lane = threadIdx.x & 63, wave = threadIdx.x >> 6;
    const int r16 = lane & 15, c4 = lane >> 4;
    const int q0  = qt * 128 + wave * 32;
    const int swz = (r16 & 7) << 4;

    const bf16* qp = qbuf + (size_t)bh * SP * 64;
    const bf16* kp = kbuf + (size_t)bh * SP * 64;
    const bf16* vp = vT   + (size_t)bh * 64 * SP;

    bf16x8 aq[2][2];
    #pragma unroll
    for (int qf = 0; qf < 2; ++qf)
        #pragma unroll
        for (int c = 0; c < 2; ++c)
            aq[qf][c] = *(const bf16x8*)(qp + (size_t)(q0 + qf * 16 + r16) * 64 + c * 32 + c4 * 8);

    float mi[2] = {-3.0e38f, -3.0e38f};
    float li[2] = {0.0f, 0.0f};
    f32x4 accO[2][4];
    #pragma unroll
    for (int qf = 0; qf < 2; ++qf)
        #pragma unroll
        for (int nt = 0; nt < 4; ++nt)
            #pragma unroll
            for (int r = 0; r < 4; ++r) accO[qf][nt][r] = 0.0f;

    char* pbase = Pls + wave * 4096 + r16 * 128;       // + qf*2048 + swizzled col

    for (int kt = 0; kt < 10; ++kt) {
        // K tile fragments (shared across both q-frags)
        bf16x8 kf[4][2];
        #pragma unroll
        for (int nt = 0; nt < 4; ++nt)
            #pragma unroll
            for (int c = 0; c < 2; ++c)
                kf[nt][c] = *(const bf16x8*)(kp + (size_t)(kt * 64 + nt * 16 + r16) * 64 + c * 32 + c4 * 8);

        #pragma unroll
        for (int qf = 0; qf < 2; ++qf) {
            // S^T = K · Q^T : D col(lane&15)=q-row, D row(c4*4+r)=k
            f32x4 sc[4];
            #pragma unroll
            for (int nt = 0; nt < 4; ++nt) {
                #pragma unroll
                for (int r = 0; r < 4; ++r) sc[nt][r] = 0.0f;
                #pragma unroll
                for (int c = 0; c < 2; ++c)
                    sc[nt] = __builtin_amdgcn_mfma_f32_16x16x32_bf16(kf[nt][c], aq[qf][c], sc[nt], 0, 0, 0);
            }
            if (kt == 9) {   // mask invalid keys (only k=576 valid in last tile)
                #pragma unroll
                for (int nt = 0; nt < 4; ++nt)
                    #pragma unroll
                    for (int r = 0; r < 4; ++r)
                        if (kt * 64 + nt * 16 + c4 * 4 + r >= S_) sc[nt][r] = -3.0e38f;
            }
            // row max: 16 local values + 2 shfls (lanes sharing r16 differ only in c4)
            float pmax = sc[0][0];
            #pragma unroll
            for (int nt = 0; nt < 4; ++nt)
                #pragma unroll
                for (int r = 0; r < 4; ++r) pmax = fmaxf(pmax, sc[nt][r]);
            pmax = fmaxf(pmax, __shfl_xor(pmax, 16));
            pmax = fmaxf(pmax, __shfl_xor(pmax, 32));

            const bool vrow = (q0 + qf * 16 + r16) < S_;
            int ok = (!vrow) || (pmax <= mi[qf] + 8.0f);
            if (!__all(ok)) {
                float mnew = fmaxf(mi[qf], pmax);
                float fsc  = __expf(mi[qf] - mnew);
                mi[qf] = mnew;
                li[qf] *= fsc;
                float fs0 = __shfl(fsc, c4 * 4 + 0);
                float fs1 = __shfl(fsc, c4 * 4 + 1);
                float fs2 = __shfl(fsc, c4 * 4 + 2);
                float fs3 = __shfl(fsc, c4 * 4 + 3);
                #pragma unroll
                for (int nt = 0; nt < 4; ++nt) {
                    accO[qf][nt][0] *= fs0; accO[qf][nt][1] *= fs1;
                    accO[qf][nt][2] *= fs2; accO[qf][nt][3] *= fs3;
                }
            }
            float p[4][4];
            float rs = 0.0f;
            #pragma unroll
            for (int nt = 0; nt < 4; ++nt)
                #pragma unroll
                for (int r = 0; r < 4; ++r) {
                    p[nt][r] = __expf(sc[nt][r] - mi[qf]);
                    rs += p[nt][r];
                }
            rs += __shfl_xor(rs, 16);
            rs += __shfl_xor(rs, 32);
            li[qf] += rs;
            // P -> LDS: one b64 per nt, XOR-swizzled (row = q-row = r16)
            #pragma unroll
            for (int nt = 0; nt < 4; ++nt) {
                bf16x4 pk;
                pk[0] = (bf16)p[nt][0]; pk[1] = (bf16)p[nt][1];
                pk[2] = (bf16)p[nt][2]; pk[3] = (bf16)p[nt][3];
                *(bf16x4*)(pbase + qf * 2048 + ((nt * 32 + c4 * 8) ^ swz)) = pk;
            }
        }

        // PV: O += P · V  (vT rows = dh)
        bf16x8 vf[4][2];
        #pragma unroll
        for (int ntd = 0; ntd < 4; ++ntd)
            #pragma unroll
            for (int kk = 0; kk < 2; ++kk)
                vf[ntd][kk] = *(const bf16x8*)(vp + (size_t)(ntd * 16 + r16) * SP + kt * 64 + kk * 32 + c4 * 8);
        #pragma unroll
        for (int qf = 0; qf < 2; ++qf) {
            bf16x8 pf[2];
            #pragma unroll
            for (int kk = 0; kk < 2; ++kk)
                pf[kk] = *(const bf16x8*)(pbase + qf * 2048 + ((kk * 64 + c4 * 16) ^ swz));
            #pragma unroll
            for (int ntd = 0; ntd < 4; ++ntd)
                #pragma unroll
                for (int kk = 0; kk < 2; ++kk)
                    accO[qf][ntd] = __builtin_amdgcn_mfma_f32_16x16x32_bf16(pf[kk], vf[ntd][kk], accO[qf][ntd], 0, 0, 0);
        }
    }

    // epilogue: divide by li (broadcast to accO's row layout) and store
    #pragma unroll
    for (int qf = 0; qf < 2; ++qf) {
        float inv = 1.0f / li[qf];
        float rl0 = __shfl(inv, c4 * 4 + 0);
        float rl1 = __shfl(inv, c4 * 4 + 1);
        float rl2 = __shfl(inv, c4 * 4 + 2);
        float rl3 = __shfl(inv, c4 * 4 + 3);
        #pragma unroll
        for (int ntd = 0; ntd < 4; ++ntd) {
            #pragma unroll
            for (int r = 0; r < 4; ++r) {
                int s = q0 + qf * 16 + c4 * 4 + r;
                if (s < S_) {
                    float rl = (r == 0) ? rl0 : (r == 1) ? rl1 : (r == 2) ? rl2 : rl3;
                    obuf[((size_t)(b * S_ + s)) * 1024 + h * 64 + ntd * 16 + r16] =
                        (bf16)(accO[qf][ntd][r] * rl);
                }
            }
        }
    }
}

extern "C" void kernel_launch(void* const* d_in, const int* in_sizes, int n_in,
                              void* d_out, int out_size, void* d_ws, size_t ws_size,
                              hipStream_t stream) {
    const float* hs = (const float*)d_in[0];
    const float* qw = (const float*)d_in[1];
    const float* qb = (const float*)d_in[2];
    const float* kw = (const float*)d_in[3];
    const float* kb = (const float*)d_in[4];
    const float* vw = (const float*)d_in[5];
    const float* vb = (const float*)d_in[6];
    const float* ow = (const float*)d_in[7];
    const float* ob = (const float*)d_in[8];

    char* ws = (char*)d_ws;
    size_t off = 0;
    auto alloc = [&](size_t bytes) { void* p = ws + off; off += (bytes + 255) & ~255UL; return p; };
    bf16* hsA  = (bf16*)alloc((size_t)MP_ * 1024 * 2);   // hidden bf16, reused as attention output
    bf16* wqkv = (bf16*)alloc((size_t)3072 * 1024 * 2);
    bf16* wo   = (bf16*)alloc((size_t)1024 * 1024 * 2);
    bf16* qbuf = (bf16*)alloc((size_t)BH_ * SP * 64 * 2);
    bf16* kbuf = (bf16*)alloc((size_t)BH_ * SP * 64 * 2);
    bf16* vT   = (bf16*)alloc((size_t)BH_ * 64 * SP * 2);

    // zero vT so padded key columns can never inject NaN/Inf into PV
    hipMemsetAsync(vT, 0, (size_t)BH_ * 64 * SP * 2, stream);

    int n4h = M_ * 1024 / 4;
    cast_kernel<<<(n4h + 255) / 256, 256, 0, stream>>>(hs, hsA, n4h);
    cast_kernel<<<1024, 256, 0, stream>>>(qw, wqkv,            262144);
    cast_kernel<<<1024, 256, 0, stream>>>(kw, wqkv + 1048576,  262144);
    cast_kernel<<<1024, 256, 0, stream>>>(vw, wqkv + 2097152,  262144);
    cast_kernel<<<1024, 256, 0, stream>>>(ow, wo,              262144);

    gemm_qkv<<<145 * 24, 256, 0, stream>>>(hsA, wqkv, qb, kb, vb, qbuf, kbuf, vT);
    attn_kernel<<<2560, 256, 0, stream>>>(qbuf, kbuf, vT, hsA);
    gemm_out<<<145 * 8, 256, 0, stream>>>(hsA, wo, ob, (float*)d_out);
}

// Round 3
// 498.728 us; speedup vs baseline: 1.5079x; 1.1152x over previous
//
#include <hip/hip_runtime.h>
#include <hip/hip_bf16.h>
#include <stdint.h>

#define B_   32
#define S_   577
#define SP   640
#define D_   1024
#define H_   16
#define DH   64
#define BH_  (B_*H_)
#define M_   (B_*S_)      // 18464
#define MP_  18560        // padded to 128
#define SCALE_ 0.125f

typedef __bf16 bf16;
typedef __bf16 bf16x8 __attribute__((ext_vector_type(8)));
typedef __bf16 bf16x4 __attribute__((ext_vector_type(4)));
typedef float  f32x4  __attribute__((ext_vector_type(4)));

__device__ __forceinline__ void gload16(const bf16* g, bf16* l) {
    __builtin_amdgcn_global_load_lds((__attribute__((address_space(1))) void*)g,
                                     (__attribute__((address_space(3))) void*)l, 16, 0, 0);
}

// ---------------- cast fp32 -> bf16 ----------------
__global__ void cast_kernel(const float* __restrict__ in, bf16* __restrict__ out, int n4) {
    int i = blockIdx.x * blockDim.x + threadIdx.x;
    if (i >= n4) return;
    float4 v = ((const float4*)in)[i];
    bf16x4 o;
    o[0] = (bf16)v.x; o[1] = (bf16)v.y; o[2] = (bf16)v.z; o[3] = (bf16)v.w;
    ((bf16x4*)out)[i] = o;
}

// four 1024x1024 weight casts in one launch (segments of 262144 float4)
__global__ void cast4_kernel(const float* __restrict__ w0, const float* __restrict__ w1,
                             const float* __restrict__ w2, const float* __restrict__ w3,
                             bf16* __restrict__ o0, bf16* __restrict__ o1,
                             bf16* __restrict__ o2, bf16* __restrict__ o3) {
    int i = blockIdx.x * blockDim.x + threadIdx.x;
    int seg = i >> 18, r = i & 262143;
    const float* in = (seg == 0) ? w0 : (seg == 1) ? w1 : (seg == 2) ? w2 : w3;
    bf16* out       = (seg == 0) ? o0 : (seg == 1) ? o1 : (seg == 2) ? o2 : o3;
    float4 v = ((const float4*)in)[r];
    bf16x4 o;
    o[0] = (bf16)v.x; o[1] = (bf16)v.y; o[2] = (bf16)v.z; o[3] = (bf16)v.w;
    ((bf16x4*)out)[r] = o;
}

// ---------------- shared GEMM mainloop: C = A[M,K] * B[N,K]^T, 128x128 tile ----------------
// T2 XOR swizzle: LDS dest linear (global_load_lds), global SOURCE pre-swizzled
// chunk ch=(li&7)^(row&7); ds_read uses chunk c=(kk*4+c4)^(row&7).
// 16 r16-lanes then hit 8 distinct 16B slots (2-way residual = free).
__device__ __forceinline__ void gemm_core(const bf16* __restrict__ A, const bf16* __restrict__ B,
                                          int m0, int n0, int K,
                                          bf16* As, bf16* Bs, f32x4 acc[4][4]) {
    const int tid  = threadIdx.x;
    const int lane = tid & 63;
    const int wave = tid >> 6;
    const int wr = wave >> 1, wc = wave & 1;
    const int r16 = lane & 15, c4 = lane >> 4;

    #pragma unroll
    for (int i = 0; i < 4; ++i)
        #pragma unroll
        for (int j = 0; j < 4; ++j)
            #pragma unroll
            for (int r = 0; r < 4; ++r) acc[i][j][r] = 0.0f;

    const int nkt = K >> 6;
    for (int kt = 0; kt < nkt; ++kt) {
        #pragma unroll
        for (int i = 0; i < 4; ++i) {
            int li  = i * 256 + tid;
            int row = li >> 3;
            int ch  = (li & 7) ^ (row & 7);          // pre-swizzled source chunk
            const bf16* ga = A + (size_t)(m0 + row) * K + kt * 64 + ch * 8;
            const bf16* gb = B + (size_t)(n0 + row) * K + kt * 64 + ch * 8;
            bf16* la = As + (size_t)(i * 256 + wave * 64) * 8;   // wave-uniform, linear
            bf16* lb = Bs + (size_t)(i * 256 + wave * 64) * 8;
            gload16(ga, la);
            gload16(gb, lb);
        }
        __syncthreads();
        #pragma unroll
        for (int kk = 0; kk < 2; ++kk) {
            bf16x8 af[4], bfr[4];
            #pragma unroll
            for (int i = 0; i < 4; ++i) {
                int row = wr * 64 + i * 16 + r16;
                int c   = (kk * 4 + c4) ^ (row & 7);
                af[i] = *(const bf16x8*)(As + row * 64 + c * 8);
            }
            #pragma unroll
            for (int j = 0; j < 4; ++j) {
                int row = wc * 64 + j * 16 + r16;
                int c   = (kk * 4 + c4) ^ (row & 7);
                bfr[j] = *(const bf16x8*)(Bs + row * 64 + c * 8);
            }
            #pragma unroll
            for (int i = 0; i < 4; ++i)
                #pragma unroll
                for (int j = 0; j < 4; ++j)
                    acc[i][j] = __builtin_amdgcn_mfma_f32_16x16x32_bf16(af[i], bfr[j], acc[i][j], 0, 0, 0);
        }
        __syncthreads();
    }
}

// ---------------- QKV projection GEMM ----------------
__global__ __launch_bounds__(256) void gemm_qkv(const bf16* __restrict__ A, const bf16* __restrict__ Bw,
                                                const float* __restrict__ qb, const float* __restrict__ kb,
                                                const float* __restrict__ vb,
                                                bf16* __restrict__ qbuf, bf16* __restrict__ kbuf,
                                                bf16* __restrict__ vT) {
    __shared__ __align__(16) char SM[33280];          // As(16K)+Bs(16K); reused as Ts[128][130]
    bf16* As = (bf16*)SM;
    bf16* Bs = (bf16*)(SM + 16384);
    int bx = blockIdx.x;
    bx = (bx & 7) * 435 + (bx >> 3);                  // bijective XCD swizzle (3480 = 8*435)
    int bm = bx / 24, bn = bx % 24;
    f32x4 acc[4][4];
    gemm_core(A, Bw, bm * 128, bn * 128, 1024, As, Bs, acc);

    const int tid  = threadIdx.x;
    const int lane = tid & 63;
    const int wave = tid >> 6, wr = wave >> 1, wc = wave & 1;
    const int r16 = lane & 15, c4 = lane >> 4;

    if (bn < 16) {
        // q (bn 0-7) / k (bn 8-15): direct stores (16 lanes -> 32B runs)
        const float* bias_arr = (bn < 8) ? qb : kb;
        bf16* dst = (bn < 8) ? qbuf : kbuf;
        float mul = (bn < 8) ? SCALE_ : 1.0f;
        #pragma unroll
        for (int j = 0; j < 4; ++j) {
            unsigned e = ((unsigned)(bn & 7)) * 128 + wc * 64 + j * 16 + r16;
            unsigned h = e >> 6, dh = e & 63;
            float bias = bias_arr[e];
            #pragma unroll
            for (int i = 0; i < 4; ++i) {
                #pragma unroll
                for (int r = 0; r < 4; ++r) {
                    unsigned m = bm * 128 + wr * 64 + i * 16 + c4 * 4 + r;
                    if (m >= M_) continue;
                    unsigned b = m / 577u, s = m - b * 577u;
                    unsigned bh = b * 16 + h;
                    dst[((size_t)(bh * SP + s)) * 64 + dh] = (bf16)((acc[i][j][r] + bias) * mul);
                }
            }
        }
    } else {
        // v: bounce through LDS, store coalesced along s into vT[bh*64+dh][s]
        __syncthreads();                              // everyone done with As/Bs
        bf16* Ts = (bf16*)SM;                         // [128][130]
        #pragma unroll
        for (int j = 0; j < 4; ++j) {
            unsigned nl = wc * 64 + j * 16 + r16;
            float bias = vb[(unsigned)(bn - 16) * 128 + nl];
            #pragma unroll
            for (int i = 0; i < 4; ++i) {
                #pragma unroll
                for (int r = 0; r < 4; ++r) {
                    unsigned ml = wr * 64 + i * 16 + c4 * 4 + r;
                    Ts[ml * 130 + nl] = (bf16)(acc[i][j][r] + bias);
                }
            }
        }
        __syncthreads();
        int ml = tid & 127, nh = tid >> 7;
        int gm = bm * 128 + ml;
        if (gm < M_) {
            unsigned b = (unsigned)gm / 577u, s = (unsigned)gm - b * 577u;
            unsigned e0 = (unsigned)(bn - 16) * 128 + nh * 64;   // 64-aligned
            bf16* dst = vT + ((size_t)((b * 16 + (e0 >> 6)) * 64)) * SP + s;
            const bf16* src = Ts + ml * 130 + nh * 64;
            #pragma unroll 8
            for (int j = 0; j < 64; ++j) dst[(size_t)j * SP] = src[j];
        }
    }
}

// ---------------- output projection GEMM + bias -> fp32 ----------------
__global__ __launch_bounds__(256) void gemm_out(const bf16* __restrict__ A, const bf16* __restrict__ Bw,
                                                const float* __restrict__ ob, float* __restrict__ out) {
    __shared__ __align__(16) bf16 As[128 * 64];
    __shared__ __align__(16) bf16 Bs[128 * 64];
    int bx = blockIdx.x;
    bx = (bx & 7) * 145 + (bx >> 3);                  // bijective XCD swizzle (1160 = 8*145)
    int bm = bx / 8, bn = bx % 8;
    f32x4 acc[4][4];
    gemm_core(A, Bw, bm * 128, bn * 128, 1024, As, Bs, acc);

    const int lane = threadIdx.x & 63;
    const int wave = threadIdx.x >> 6, wr = wave >> 1, wc = wave & 1;
    const int r16 = lane & 15, c4 = lane >> 4;
    #pragma unroll
    for (int j = 0; j < 4; ++j) {
        unsigned n = bn * 128 + wc * 64 + j * 16 + r16;
        float bias = ob[n];
        #pragma unroll
        for (int i = 0; i < 4; ++i) {
            #pragma unroll
            for (int r = 0; r < 4; ++r) {
                unsigned m = bm * 128 + wr * 64 + i * 16 + c4 * 4 + r;
                if (m < M_) out[(size_t)m * 1024 + n] = acc[i][j][r] + bias;
            }
        }
    }
}

// ---------------- flash attention (unchanged from R2) ----------------
__global__ __launch_bounds__(256) void attn_kernel(const bf16* __restrict__ qbuf, const bf16* __restrict__ kbuf,
                                                   const bf16* __restrict__ vT, bf16* __restrict__ obuf) {
    __shared__ __align__(16) char Pls[4 * 2 * 2048];
    const int orig = blockIdx.x;
    const int xcd = orig & 7;
    const int t   = orig >> 3;
    const int qt  = t % 5, bhg = t / 5;
    const int bh  = bhg * 8 + xcd;
    const int b   = bh >> 4, h = bh & 15;
    const int lane = threadIdx.x & 63, wave = threadIdx.x >> 6;
    const int r16 = lane & 15, c4 = lane >> 4;
    const int q0  = qt * 128 + wave * 32;
    const int swz = (r16 & 7) << 4;

    const bf16* qp = qbuf + (size_t)bh * SP * 64;
    const bf16* kp = kbuf + (size_t)bh * SP * 64;
    const bf16* vp = vT   + (size_t)bh * 64 * SP;

    bf16x8 aq[2][2];
    #pragma unroll
    for (int qf = 0; qf < 2; ++qf)
        #pragma unroll
        for (int c = 0; c < 2; ++c)
            aq[qf][c] = *(const bf16x8*)(qp + (size_t)(q0 + qf * 16 + r16) * 64 + c * 32 + c4 * 8);

    float mi[2] = {-3.0e38f, -3.0e38f};
    float li[2] = {0.0f, 0.0f};
    f32x4 accO[2][4];
    #pragma unroll
    for (int qf = 0; qf < 2; ++qf)
        #pragma unroll
        for (int nt = 0; nt < 4; ++nt)
            #pragma unroll
            for (int r = 0; r < 4; ++r) accO[qf][nt][r] = 0.0f;

    char* pbase = Pls + wave * 4096 + r16 * 128;

    for (int kt = 0; kt < 10; ++kt) {
        bf16x8 kf[4][2];
        #pragma unroll
        for (int nt = 0; nt < 4; ++nt)
            #pragma unroll
            for (int c = 0; c < 2; ++c)
                kf[nt][c] = *(const bf16x8*)(kp + (size_t)(kt * 64 + nt * 16 + r16) * 64 + c * 32 + c4 * 8);

        #pragma unroll
        for (int qf = 0; qf < 2; ++qf) {
            f32x4 sc[4];
            #pragma unroll
            for (int nt = 0; nt < 4; ++nt) {
                #pragma unroll
                for (int r = 0; r < 4; ++r) sc[nt][r] = 0.0f;
                #pragma unroll
                for (int c = 0; c < 2; ++c)
                    sc[nt] = __builtin_amdgcn_mfma_f32_16x16x32_bf16(kf[nt][c], aq[qf][c], sc[nt], 0, 0, 0);
            }
            if (kt == 9) {
                #pragma unroll
                for (int nt = 0; nt < 4; ++nt)
                    #pragma unroll
                    for (int r = 0; r < 4; ++r)
                        if (kt * 64 + nt * 16 + c4 * 4 + r >= S_) sc[nt][r] = -3.0e38f;
            }
            float pmax = sc[0][0];
            #pragma unroll
            for (int nt = 0; nt < 4; ++nt)
                #pragma unroll
                for (int r = 0; r < 4; ++r) pmax = fmaxf(pmax, sc[nt][r]);
            pmax = fmaxf(pmax, __shfl_xor(pmax, 16));
            pmax = fmaxf(pmax, __shfl_xor(pmax, 32));

            const bool vrow = (q0 + qf * 16 + r16) < S_;
            int ok = (!vrow) || (pmax <= mi[qf] + 8.0f);
            if (!__all(ok)) {
                float mnew = fmaxf(mi[qf], pmax);
                float fsc  = __expf(mi[qf] - mnew);
                mi[qf] = mnew;
                li[qf] *= fsc;
                float fs0 = __shfl(fsc, c4 * 4 + 0);
                float fs1 = __shfl(fsc, c4 * 4 + 1);
                float fs2 = __shfl(fsc, c4 * 4 + 2);
                float fs3 = __shfl(fsc, c4 * 4 + 3);
                #pragma unroll
                for (int nt = 0; nt < 4; ++nt) {
                    accO[qf][nt][0] *= fs0; accO[qf][nt][1] *= fs1;
                    accO[qf][nt][2] *= fs2; accO[qf][nt][3] *= fs3;
                }
            }
            float p[4][4];
            float rs = 0.0f;
            #pragma unroll
            for (int nt = 0; nt < 4; ++nt)
                #pragma unroll
                for (int r = 0; r < 4; ++r) {
                    p[nt][r] = __expf(sc[nt][r] - mi[qf]);
                    rs += p[nt][r];
                }
            rs += __shfl_xor(rs, 16);
            rs += __shfl_xor(rs, 32);
            li[qf] += rs;
            #pragma unroll
            for (int nt = 0; nt < 4; ++nt) {
                bf16x4 pk;
                pk[0] = (bf16)p[nt][0]; pk[1] = (bf16)p[nt][1];
                pk[2] = (bf16)p[nt][2]; pk[3] = (bf16)p[nt][3];
                *(bf16x4*)(pbase + qf * 2048 + ((nt * 32 + c4 * 8) ^ swz)) = pk;
            }
        }

        bf16x8 vf[4][2];
        #pragma unroll
        for (int ntd = 0; ntd < 4; ++ntd)
            #pragma unroll
            for (int kk = 0; kk < 2; ++kk)
                vf[ntd][kk] = *(const bf16x8*)(vp + (size_t)(ntd * 16 + r16) * SP + kt * 64 + kk * 32 + c4 * 8);
        #pragma unroll
        for (int qf = 0; qf < 2; ++qf) {
            bf16x8 pf[2];
            #pragma unroll
            for (int kk = 0; kk < 2; ++kk)
                pf[kk] = *(const bf16x8*)(pbase + qf * 2048 + ((kk * 64 + c4 * 16) ^ swz));
            #pragma unroll
            for (int ntd = 0; ntd < 4; ++ntd)
                #pragma unroll
                for (int kk = 0; kk < 2; ++kk)
                    accO[qf][ntd] = __builtin_amdgcn_mfma_f32_16x16x32_bf16(pf[kk], vf[ntd][kk], accO[qf][ntd], 0, 0, 0);
        }
    }

    #pragma unroll
    for (int qf = 0; qf < 2; ++qf) {
        float inv = 1.0f / li[qf];
        float rl0 = __shfl(inv, c4 * 4 + 0);
        float rl1 = __shfl(inv, c4 * 4 + 1);
        float rl2 = __shfl(inv, c4 * 4 + 2);
        float rl3 = __shfl(inv, c4 * 4 + 3);
        #pragma unroll
        for (int ntd = 0; ntd < 4; ++ntd) {
            #pragma unroll
            for (int r = 0; r < 4; ++r) {
                int s = q0 + qf * 16 + c4 * 4 + r;
                if (s < S_) {
                    float rl = (r == 0) ? rl0 : (r == 1) ? rl1 : (r == 2) ? rl2 : rl3;
                    obuf[((size_t)(b * S_ + s)) * 1024 + h * 64 + ntd * 16 + r16] =
                        (bf16)(accO[qf][ntd][r] * rl);
                }
            }
        }
    }
}

extern "C" void kernel_launch(void* const* d_in, const int* in_sizes, int n_in,
                              void* d_out, int out_size, void* d_ws, size_t ws_size,
                              hipStream_t stream) {
    const float* hs = (const float*)d_in[0];
    const float* qw = (const float*)d_in[1];
    const float* qb = (const float*)d_in[2];
    const float* kw = (const float*)d_in[3];
    const float* kb = (const float*)d_in[4];
    const float* vw = (const float*)d_in[5];
    const float* vb = (const float*)d_in[6];
    const float* ow = (const float*)d_in[7];
    const float* ob = (const float*)d_in[8];

    char* ws = (char*)d_ws;
    size_t off = 0;
    auto alloc = [&](size_t bytes) { void* p = ws + off; off += (bytes + 255) & ~255UL; return p; };
    bf16* hsA  = (bf16*)alloc((size_t)MP_ * 1024 * 2);
    bf16* wqkv = (bf16*)alloc((size_t)3072 * 1024 * 2);
    bf16* wo   = (bf16*)alloc((size_t)1024 * 1024 * 2);
    bf16* qbuf = (bf16*)alloc((size_t)BH_ * SP * 64 * 2);
    bf16* kbuf = (bf16*)alloc((size_t)BH_ * SP * 64 * 2);
    bf16* vT   = (bf16*)alloc((size_t)BH_ * 64 * SP * 2);

    hipMemsetAsync(vT, 0, (size_t)BH_ * 64 * SP * 2, stream);

    int n4h = M_ * 1024 / 4;
    cast_kernel<<<(n4h + 255) / 256, 256, 0, stream>>>(hs, hsA, n4h);
    cast4_kernel<<<4096, 256, 0, stream>>>(qw, kw, vw, ow,
                                           wqkv, wqkv + 1048576, wqkv + 2097152, wo);

    gemm_qkv<<<145 * 24, 256, 0, stream>>>(hsA, wqkv, qb, kb, vb, qbuf, kbuf, vT);
    attn_kernel<<<2560, 256, 0, stream>>>(qbuf, kbuf, vT, hsA);
    gemm_out<<<145 * 8, 256, 0, stream>>>(hsA, wo, ob, (float*)d_out);
}

// Round 4
// 451.297 us; speedup vs baseline: 1.6664x; 1.1051x over previous
//
#include <hip/hip_runtime.h>
#include <hip/hip_bf16.h>
#include <stdint.h>

#define B_   32
#define S_   577
#define SP   640
#define D_   1024
#define H_   16
#define DH   64
#define BH_  (B_*H_)
#define M_   (B_*S_)      // 18464
#define MP2  18688        // padded to 256
#define SCALE_ 0.125f

typedef __bf16 bf16;
typedef __bf16 bf16x8 __attribute__((ext_vector_type(8)));
typedef __bf16 bf16x4 __attribute__((ext_vector_type(4)));
typedef float  f32x4  __attribute__((ext_vector_type(4)));

__device__ __forceinline__ void gload16(const bf16* g, bf16* l) {
    __builtin_amdgcn_global_load_lds((__attribute__((address_space(1))) void*)g,
                                     (__attribute__((address_space(3))) void*)l, 16, 0, 0);
}

// ---------------- cast fp32 -> bf16 ----------------
__global__ void cast_kernel(const float* __restrict__ in, bf16* __restrict__ out, int n4) {
    int i = blockIdx.x * blockDim.x + threadIdx.x;
    if (i >= n4) return;
    float4 v = ((const float4*)in)[i];
    bf16x4 o;
    o[0] = (bf16)v.x; o[1] = (bf16)v.y; o[2] = (bf16)v.z; o[3] = (bf16)v.w;
    ((bf16x4*)out)[i] = o;
}

__global__ void cast4_kernel(const float* __restrict__ w0, const float* __restrict__ w1,
                             const float* __restrict__ w2, const float* __restrict__ w3,
                             bf16* __restrict__ o0, bf16* __restrict__ o1,
                             bf16* __restrict__ o2, bf16* __restrict__ o3) {
    int i = blockIdx.x * blockDim.x + threadIdx.x;
    int seg = i >> 18, r = i & 262143;
    const float* in = (seg == 0) ? w0 : (seg == 1) ? w1 : (seg == 2) ? w2 : w3;
    bf16* out       = (seg == 0) ? o0 : (seg == 1) ? o1 : (seg == 2) ? o2 : o3;
    float4 v = ((const float4*)in)[r];
    bf16x4 o;
    o[0] = (bf16)v.x; o[1] = (bf16)v.y; o[2] = (bf16)v.z; o[3] = (bf16)v.w;
    ((bf16x4*)out)[r] = o;
}

// ---------------- 256x256 tile, BK=64, double-buffered 2-phase GEMM core ----------------
// 512 threads = 8 waves (2M x 4N), per-wave 128x64 output = acc[8][4].
// LDS: 2 bufs x (A 256x64 + B 256x64) bf16 = 128 KB.
// XOR swizzle: source chunk ch=(li&7)^(row&7), read chunk c=(kk*4+c4)^(row&7).
// Race-free: stage(kt+1, buf^1) || compute(kt, buf); __syncthreads drains vm+lgkm.
__device__ __forceinline__ void stage256(const bf16* __restrict__ A, const bf16* __restrict__ B,
                                         int m0, int n0, int K, int kt, bf16* SMbuf) {
    const int tid = threadIdx.x;
    const int wave = tid >> 6;
    #pragma unroll
    for (int ld = 0; ld < 8; ++ld) {
        int li  = ld * 512 + tid;
        int row = (li >> 3) & 255;
        int ch  = (li & 7) ^ (row & 7);
        const bf16* g = ((ld < 4) ? (A + (size_t)(m0 + row) * K)
                                  : (B + (size_t)(n0 + row) * K)) + kt * 64 + ch * 8;
        bf16* l = SMbuf + (size_t)(ld * 512 + wave * 64) * 8;   // wave-uniform base
        gload16(g, l);
    }
}

__device__ __forceinline__ void compute256(const bf16* SMbuf, f32x4 acc[8][4],
                                           int wm, int wn, int r16, int c4) {
    #pragma unroll
    for (int kk = 0; kk < 2; ++kk) {
        bf16x8 bq[4];
        #pragma unroll
        for (int j = 0; j < 4; ++j) {
            int row = wn * 64 + j * 16 + r16;
            int c   = (kk * 4 + c4) ^ (row & 7);
            bq[j] = *(const bf16x8*)(SMbuf + 16384 + row * 64 + c * 8);
        }
        #pragma unroll
        for (int i = 0; i < 8; ++i) {
            int row = wm * 128 + i * 16 + r16;
            int c   = (kk * 4 + c4) ^ (row & 7);
            bf16x8 a = *(const bf16x8*)(SMbuf + row * 64 + c * 8);
            #pragma unroll
            for (int j = 0; j < 4; ++j)
                acc[i][j] = __builtin_amdgcn_mfma_f32_16x16x32_bf16(a, bq[j], acc[i][j], 0, 0, 0);
        }
    }
}

// ---------------- QKV projection: [MP2,1024] x [3072,1024]^T ----------------
// bn 0-3: Q -> qk cols [0,1024); bn 4-7: K -> qk cols [1024,2048); bn 8-11: V -> vT
__global__ __launch_bounds__(512, 2) void gemm_qkv(const bf16* __restrict__ A, const bf16* __restrict__ Bw,
                                                   const float* __restrict__ qb, const float* __restrict__ kb,
                                                   const float* __restrict__ vb,
                                                   bf16* __restrict__ qk, bf16* __restrict__ vT) {
    __shared__ __align__(16) bf16 SM[2 * 32768];   // 128 KB
    const int bx = blockIdx.x;
    const int bm = bx / 12, bn = bx % 12;          // natural order: bn fastest (L2 panel reuse)
    const int m0 = bm * 256, n0 = bn * 256;
    const int tid = threadIdx.x;
    const int lane = tid & 63, wave = tid >> 6;
    const int wm = wave >> 2, wn = wave & 3;
    const int r16 = lane & 15, c4 = lane >> 4;

    f32x4 acc[8][4];
    #pragma unroll
    for (int i = 0; i < 8; ++i)
        #pragma unroll
        for (int j = 0; j < 4; ++j)
            #pragma unroll
            for (int r = 0; r < 4; ++r) acc[i][j][r] = 0.0f;

    stage256(A, Bw, m0, n0, 1024, 0, SM);
    __syncthreads();
    for (int kt = 0; kt < 16; ++kt) {
        if (kt < 15) stage256(A, Bw, m0, n0, 1024, kt + 1, SM + ((kt + 1) & 1) * 32768);
        compute256(SM + (kt & 1) * 32768, acc, wm, wn, r16, c4);
        __syncthreads();
    }

    if (bn < 8) {
        // Q or K: direct stores into qk[M][2048]
        const float* barr = (bn < 4) ? qb : kb;
        const float mul = (bn < 4) ? SCALE_ : 1.0f;
        #pragma unroll
        for (int j = 0; j < 4; ++j) {
            int n = n0 + wn * 64 + j * 16 + r16;
            float bias = barr[n & 1023];
            #pragma unroll
            for (int i = 0; i < 8; ++i) {
                #pragma unroll
                for (int r = 0; r < 4; ++r) {
                    int m = m0 + wm * 128 + i * 16 + c4 * 4 + r;
                    if (m < M_) qk[(size_t)m * 2048 + n] = (bf16)((acc[i][j][r] + bias) * mul);
                }
            }
        }
    } else {
        // V: bounce through LDS (two 128-row rounds), coalesced store along s into vT
        const int bnp = bn - 8;
        bf16* Ts = SM;                              // [128][259]
        #pragma unroll
        for (int mh = 0; mh < 2; ++mh) {
            if (wm == mh) {
                #pragma unroll
                for (int j = 0; j < 4; ++j) {
                    int nl = wn * 64 + j * 16 + r16;
                    float bias = vb[bnp * 256 + nl];
                    #pragma unroll
                    for (int i = 0; i < 8; ++i) {
                        #pragma unroll
                        for (int r = 0; r < 4; ++r) {
                            int tr = i * 16 + c4 * 4 + r;
                            Ts[tr * 259 + nl] = (bf16)(acc[i][j][r] + bias);
                        }
                    }
                }
            }
            __syncthreads();
            {
                int ml = tid & 127, nh = tid >> 7;
                int gm = m0 + mh * 128 + ml;
                if (gm < M_) {
                    unsigned bb = (unsigned)gm / 577u, s = (unsigned)gm - bb * 577u;
                    bf16* dst = vT + ((size_t)((bb * 16 + bnp * 4 + nh) * 64)) * SP + s;
                    const bf16* src = Ts + ml * 259 + nh * 64;
                    #pragma unroll 8
                    for (int j = 0; j < 64; ++j) dst[(size_t)j * SP] = src[j];
                }
            }
            __syncthreads();
        }
    }
}

// ---------------- output projection: [MP2,1024] x [1024,1024]^T + bias -> fp32 ----------------
__global__ __launch_bounds__(512, 2) void gemm_out(const bf16* __restrict__ A, const bf16* __restrict__ Bw,
                                                   const float* __restrict__ ob, float* __restrict__ out) {
    __shared__ __align__(16) bf16 SM[2 * 32768];
    const int bx = blockIdx.x;
    const int bm = bx >> 2, bn = bx & 3;
    const int m0 = bm * 256, n0 = bn * 256;
    const int tid = threadIdx.x;
    const int lane = tid & 63, wave = tid >> 6;
    const int wm = wave >> 2, wn = wave & 3;
    const int r16 = lane & 15, c4 = lane >> 4;

    f32x4 acc[8][4];
    #pragma unroll
    for (int i = 0; i < 8; ++i)
        #pragma unroll
        for (int j = 0; j < 4; ++j)
            #pragma unroll
            for (int r = 0; r < 4; ++r) acc[i][j][r] = 0.0f;

    stage256(A, Bw, m0, n0, 1024, 0, SM);
    __syncthreads();
    for (int kt = 0; kt < 16; ++kt) {
        if (kt < 15) stage256(A, Bw, m0, n0, 1024, kt + 1, SM + ((kt + 1) & 1) * 32768);
        compute256(SM + (kt & 1) * 32768, acc, wm, wn, r16, c4);
        __syncthreads();
    }

    #pragma unroll
    for (int j = 0; j < 4; ++j) {
        int n = n0 + wn * 64 + j * 16 + r16;
        float bias = ob[n];
        #pragma unroll
        for (int i = 0; i < 8; ++i) {
            #pragma unroll
            for (int r = 0; r < 4; ++r) {
                int m = m0 + wm * 128 + i * 16 + c4 * 4 + r;
                if (m < M_) out[(size_t)m * 1024 + n] = acc[i][j][r] + bias;
            }
        }
    }
}

// ---------------- flash attention (R3 structure; q/k now read from qk[M][2048]) ----------------
__global__ __launch_bounds__(256) void attn_kernel(const bf16* __restrict__ qk,
                                                   const bf16* __restrict__ vT, bf16* __restrict__ obuf) {
    __shared__ __align__(16) char Pls[4 * 2 * 2048];
    const int orig = blockIdx.x;
    const int xcd = orig & 7;
    const int t   = orig >> 3;
    const int qt  = t % 5, bhg = t / 5;
    const int bh  = bhg * 8 + xcd;
    const int b   = bh >> 4, h = bh & 15;
    const int lane = threadIdx.x & 63, wave = threadIdx.x >> 6;
    const int r16 = lane & 15, c4 = lane >> 4;
    const int q0  = qt * 128 + wave * 32;
    const int swz = (r16 & 7) << 4;

    const bf16* qp = qk + (size_t)(b * 577) * 2048 + h * 64;
    const bf16* kp = qp + 1024;
    const bf16* vp = vT + (size_t)bh * 64 * SP;

    bf16x8 aq[2][2];
    #pragma unroll
    for (int qf = 0; qf < 2; ++qf)
        #pragma unroll
        for (int c = 0; c < 2; ++c)
            aq[qf][c] = *(const bf16x8*)(qp + (size_t)(q0 + qf * 16 + r16) * 2048 + c * 32 + c4 * 8);

    float mi[2] = {-3.0e38f, -3.0e38f};
    float li[2] = {0.0f, 0.0f};
    f32x4 accO[2][4];
    #pragma unroll
    for (int qf = 0; qf < 2; ++qf)
        #pragma unroll
        for (int nt = 0; nt < 4; ++nt)
            #pragma unroll
            for (int r = 0; r < 4; ++r) accO[qf][nt][r] = 0.0f;

    char* pbase = Pls + wave * 4096 + r16 * 128;

    for (int kt = 0; kt < 10; ++kt) {
        bf16x8 kf[4][2];
        #pragma unroll
        for (int nt = 0; nt < 4; ++nt)
            #pragma unroll
            for (int c = 0; c < 2; ++c)
                kf[nt][c] = *(const bf16x8*)(kp + (size_t)(kt * 64 + nt * 16 + r16) * 2048 + c * 32 + c4 * 8);

        #pragma unroll
        for (int qf = 0; qf < 2; ++qf) {
            f32x4 sc[4];
            #pragma unroll
            for (int nt = 0; nt < 4; ++nt) {
                #pragma unroll
                for (int r = 0; r < 4; ++r) sc[nt][r] = 0.0f;
                #pragma unroll
                for (int c = 0; c < 2; ++c)
                    sc[nt] = __builtin_amdgcn_mfma_f32_16x16x32_bf16(kf[nt][c], aq[qf][c], sc[nt], 0, 0, 0);
            }
            if (kt == 9) {
                #pragma unroll
                for (int nt = 0; nt < 4; ++nt)
                    #pragma unroll
                    for (int r = 0; r < 4; ++r)
                        if (kt * 64 + nt * 16 + c4 * 4 + r >= S_) sc[nt][r] = -3.0e38f;
            }
            float pmax = sc[0][0];
            #pragma unroll
            for (int nt = 0; nt < 4; ++nt)
                #pragma unroll
                for (int r = 0; r < 4; ++r) pmax = fmaxf(pmax, sc[nt][r]);
            pmax = fmaxf(pmax, __shfl_xor(pmax, 16));
            pmax = fmaxf(pmax, __shfl_xor(pmax, 32));

            const bool vrow = (q0 + qf * 16 + r16) < S_;
            int ok = (!vrow) || (pmax <= mi[qf] + 8.0f);
            if (!__all(ok)) {
                float mnew = fmaxf(mi[qf], pmax);
                float fsc  = __expf(mi[qf] - mnew);
                mi[qf] = mnew;
                li[qf] *= fsc;
                float fs0 = __shfl(fsc, c4 * 4 + 0);
                float fs1 = __shfl(fsc, c4 * 4 + 1);
                float fs2 = __shfl(fsc, c4 * 4 + 2);
                float fs3 = __shfl(fsc, c4 * 4 + 3);
                #pragma unroll
                for (int nt = 0; nt < 4; ++nt) {
                    accO[qf][nt][0] *= fs0; accO[qf][nt][1] *= fs1;
                    accO[qf][nt][2] *= fs2; accO[qf][nt][3] *= fs3;
                }
            }
            float p[4][4];
            float rs = 0.0f;
            #pragma unroll
            for (int nt = 0; nt < 4; ++nt)
                #pragma unroll
                for (int r = 0; r < 4; ++r) {
                    p[nt][r] = __expf(sc[nt][r] - mi[qf]);
                    rs += p[nt][r];
                }
            rs += __shfl_xor(rs, 16);
            rs += __shfl_xor(rs, 32);
            li[qf] += rs;
            #pragma unroll
            for (int nt = 0; nt < 4; ++nt) {
                bf16x4 pk;
                pk[0] = (bf16)p[nt][0]; pk[1] = (bf16)p[nt][1];
                pk[2] = (bf16)p[nt][2]; pk[3] = (bf16)p[nt][3];
                *(bf16x4*)(pbase + qf * 2048 + ((nt * 32 + c4 * 8) ^ swz)) = pk;
            }
        }

        bf16x8 vf[4][2];
        #pragma unroll
        for (int ntd = 0; ntd < 4; ++ntd)
            #pragma unroll
            for (int kk = 0; kk < 2; ++kk)
                vf[ntd][kk] = *(const bf16x8*)(vp + (size_t)(ntd * 16 + r16) * SP + kt * 64 + kk * 32 + c4 * 8);
        #pragma unroll
        for (int qf = 0; qf < 2; ++qf) {
            bf16x8 pf[2];
            #pragma unroll
            for (int kk = 0; kk < 2; ++kk)
                pf[kk] = *(const bf16x8*)(pbase + qf * 2048 + ((kk * 64 + c4 * 16) ^ swz));
            #pragma unroll
            for (int ntd = 0; ntd < 4; ++ntd)
                #pragma unroll
                for (int kk = 0; kk < 2; ++kk)
                    accO[qf][ntd] = __builtin_amdgcn_mfma_f32_16x16x32_bf16(pf[kk], vf[ntd][kk], accO[qf][ntd], 0, 0, 0);
        }
    }

    #pragma unroll
    for (int qf = 0; qf < 2; ++qf) {
        float inv = 1.0f / li[qf];
        float rl0 = __shfl(inv, c4 * 4 + 0);
        float rl1 = __shfl(inv, c4 * 4 + 1);
        float rl2 = __shfl(inv, c4 * 4 + 2);
        float rl3 = __shfl(inv, c4 * 4 + 3);
        #pragma unroll
        for (int ntd = 0; ntd < 4; ++ntd) {
            #pragma unroll
            for (int r = 0; r < 4; ++r) {
                int s = q0 + qf * 16 + c4 * 4 + r;
                if (s < S_) {
                    float rl = (r == 0) ? rl0 : (r == 1) ? rl1 : (r == 2) ? rl2 : rl3;
                    obuf[((size_t)(b * S_ + s)) * 1024 + h * 64 + ntd * 16 + r16] =
                        (bf16)(accO[qf][ntd][r] * rl);
                }
            }
        }
    }
}

extern "C" void kernel_launch(void* const* d_in, const int* in_sizes, int n_in,
                              void* d_out, int out_size, void* d_ws, size_t ws_size,
                              hipStream_t stream) {
    const float* hs = (const float*)d_in[0];
    const float* qw = (const float*)d_in[1];
    const float* qb = (const float*)d_in[2];
    const float* kw = (const float*)d_in[3];
    const float* kb = (const float*)d_in[4];
    const float* vw = (const float*)d_in[5];
    const float* vb = (const float*)d_in[6];
    const float* ow = (const float*)d_in[7];
    const float* ob = (const float*)d_in[8];

    char* ws = (char*)d_ws;
    size_t off = 0;
    auto alloc = [&](size_t bytes) { void* p = ws + off; off += (bytes + 255) & ~255UL; return p; };
    bf16* hsA  = (bf16*)alloc((size_t)MP2 * 1024 * 2);   // hidden bf16; reused as attention output
    bf16* wqkv = (bf16*)alloc((size_t)3072 * 1024 * 2);
    bf16* wo   = (bf16*)alloc((size_t)1024 * 1024 * 2);
    bf16* qk   = (bf16*)alloc((size_t)MP2 * 2048 * 2);   // Q cols [0,1024), K cols [1024,2048)
    bf16* vT   = (bf16*)alloc((size_t)BH_ * 64 * SP * 2);

    hipMemsetAsync(vT, 0, (size_t)BH_ * 64 * SP * 2, stream);

    int n4h = M_ * 1024 / 4;
    cast_kernel<<<(n4h + 255) / 256, 256, 0, stream>>>(hs, hsA, n4h);
    cast4_kernel<<<4096, 256, 0, stream>>>(qw, kw, vw, ow,
                                           wqkv, wqkv + 1048576, wqkv + 2097152, wo);

    gemm_qkv<<<73 * 12, 512, 0, stream>>>(hsA, wqkv, qb, kb, vb, qk, vT);
    attn_kernel<<<2560, 256, 0, stream>>>(qk, vT, hsA);
    gemm_out<<<73 * 4, 512, 0, stream>>>(hsA, wo, ob, (float*)d_out);
}